// Round 8
// baseline (282.858 us; speedup 1.0000x reference)
//
#include <hip/hip_runtime.h>

typedef __bf16 bf16;
typedef __bf16 bf16x4 __attribute__((ext_vector_type(4)));
typedef __bf16 bf16x8 __attribute__((ext_vector_type(8)));
typedef float f32x4 __attribute__((ext_vector_type(4)));

#define TT_ 2048
#define CC_ 1024
#define HH_ 64

// scale * 1/ln(2): softmax via exp2, no max subtraction (|s|<~3, fp32-safe)
#define SCALE2 0.045084221f

#define XSTR 264   // LDS row stride (bf16): 256 cols + 8 pad -> A-frag reads 2-way (free)

// ---------------- prep: Wt[m][n][k] = W_m[k][n], fp32 -> bf16, LDS transpose --
__global__ __launch_bounds__(256) void prep_w(const float* __restrict__ Wq,
                                              const float* __restrict__ Wk,
                                              const float* __restrict__ Wv,
                                              bf16* __restrict__ Wt) {
    __shared__ bf16 Ls[64 * 65];
    const int m  = blockIdx.x >> 4;
    const int k0 = (blockIdx.x & 15) * 64;
    const float* W = (m == 0) ? Wq : (m == 1) ? Wk : Wv;
    const int tid = threadIdx.x;
    #pragma unroll
    for (int j = 0; j < 4; ++j) {
        int idx = tid + 256 * j;
        int r   = idx >> 4;
        int c4  = (idx & 15) * 4;
        float4 w = *(const float4*)&W[(size_t)(k0 + r) * HH_ + c4];
        Ls[r * 65 + c4 + 0] = (bf16)w.x;
        Ls[r * 65 + c4 + 1] = (bf16)w.y;
        Ls[r * 65 + c4 + 2] = (bf16)w.z;
        Ls[r * 65 + c4 + 3] = (bf16)w.w;
    }
    __syncthreads();
    #pragma unroll
    for (int j = 0; j < 4; ++j) {
        int idx = tid + 256 * j;
        int n   = idx >> 4;
        int kc  = (idx & 15) * 4;
        bf16x4 v;
        #pragma unroll
        for (int i = 0; i < 4; ++i) v[i] = Ls[(kc + i) * 65 + n];
        *(bf16x4*)&Wt[m * 65536 + n * 1024 + k0 + kc] = v;
    }
}

// ---------------- fused QKV projection: BK=256, deep prefetch ----------------
// 1024 blocks, M-tile 32. Per thread 8 float4 (128B) in flight -> Little's law
// BW ceiling >> HBM; 4 barriers total. LDS 33 KB (2 x 32 x 264 bf16).
__global__ __launch_bounds__(256, 2) void qkv_kernel(const float* __restrict__ x,
                                                     const bf16* __restrict__ Wt,
                                                     bf16* __restrict__ qb,
                                                     bf16* __restrict__ kb,
                                                     bf16* __restrict__ vt) {
    __shared__ __align__(16) bf16 Xs[2][32 * XSTR];
    const int tid  = threadIdx.x;
    const int wave = tid >> 6;
    const int lane = tid & 15;
    const int quad = (tid & 63) >> 4;
    const int m0   = blockIdx.x * 32;

    f32x4 acc[2][3];
    #pragma unroll
    for (int i = 0; i < 2; ++i)
        #pragma unroll
        for (int j = 0; j < 3; ++j) acc[i][j] = f32x4{0.f, 0.f, 0.f, 0.f};

    const int srow = tid >> 3;        // 0..31
    const int scol = (tid & 7) * 32;  // 0..224

    float4 xr[8];
    {
        const float* xp = &x[(size_t)(m0 + srow) * CC_ + scol];
        #pragma unroll
        for (int i = 0; i < 8; ++i) xr[i] = *(const float4*)(xp + i * 4);
    }
    #pragma unroll
    for (int i = 0; i < 4; ++i) {
        bf16x8 bv = {(bf16)xr[2*i].x, (bf16)xr[2*i].y, (bf16)xr[2*i].z, (bf16)xr[2*i].w,
                     (bf16)xr[2*i+1].x, (bf16)xr[2*i+1].y, (bf16)xr[2*i+1].z, (bf16)xr[2*i+1].w};
        *(bf16x8*)&Xs[0][srow * XSTR + scol + i * 8] = bv;
    }

    for (int kt = 0; kt < 4; ++kt) {
        const int cur = kt & 1;
        __syncthreads();
        if (kt < 3) {   // prefetch next 256-wide tile (8 float4 in flight)
            const float* xp = &x[(size_t)(m0 + srow) * CC_ + (kt + 1) * 256 + scol];
            #pragma unroll
            for (int i = 0; i < 8; ++i) xr[i] = *(const float4*)(xp + i * 4);
        }
        #pragma unroll
        for (int sub = 0; sub < 4; ++sub) {
            const int k0g = kt * 256 + sub * 64;
            const int k0l = sub * 64;
            bf16x8 bfr[2][3];
            #pragma unroll
            for (int step = 0; step < 2; ++step)
                #pragma unroll
                for (int ct = 0; ct < 3; ++ct)
                    bfr[step][ct] = *(const bf16x8*)&Wt[(size_t)(wave * 48 + ct * 16 + lane) * 1024 + k0g + step * 32 + quad * 8];
            bf16x8 afr[2][2];
            #pragma unroll
            for (int rt = 0; rt < 2; ++rt)
                #pragma unroll
                for (int step = 0; step < 2; ++step)
                    afr[rt][step] = *(const bf16x8*)&Xs[cur][(rt * 16 + lane) * XSTR + k0l + step * 32 + quad * 8];
            #pragma unroll
            for (int step = 0; step < 2; ++step)
                #pragma unroll
                for (int ct = 0; ct < 3; ++ct)
                    #pragma unroll
                    for (int rt = 0; rt < 2; ++rt)
                        acc[rt][ct] = __builtin_amdgcn_mfma_f32_16x16x32_bf16(afr[rt][step], bfr[step][ct], acc[rt][ct], 0, 0, 0);
        }
        if (kt < 3) {
            #pragma unroll
            for (int i = 0; i < 4; ++i) {
                bf16x8 bv = {(bf16)xr[2*i].x, (bf16)xr[2*i].y, (bf16)xr[2*i].z, (bf16)xr[2*i].w,
                             (bf16)xr[2*i+1].x, (bf16)xr[2*i+1].y, (bf16)xr[2*i+1].z, (bf16)xr[2*i+1].w};
                *(bf16x8*)&Xs[cur ^ 1][srow * XSTR + scol + i * 8] = bv;
            }
        }
    }

    // epilogue: C/D layout col=lane, row=quad*4+r; V transposed via Xs[0] alias
    bf16* Vsm = &Xs[0][0];            // 32 x 72 region
    const int bb = m0 >> 11;
    const int t0 = m0 & 2047;
    #pragma unroll
    for (int ct = 0; ct < 3; ++ct) {
        int c0 = wave * 48 + ct * 16;
        if (c0 < 128) {
            bf16* outp = (c0 < 64) ? qb : kb;
            int h = (c0 & 63) + lane;
            #pragma unroll
            for (int rt = 0; rt < 2; ++rt)
                #pragma unroll
                for (int r = 0; r < 4; ++r)
                    outp[(size_t)(m0 + rt * 16 + quad * 4 + r) * HH_ + h] = (bf16)acc[rt][ct][r];
        } else {
            int h = (c0 - 128) + lane;
            #pragma unroll
            for (int rt = 0; rt < 2; ++rt)
                #pragma unroll
                for (int r = 0; r < 4; ++r)
                    Vsm[(rt * 16 + quad * 4 + r) * 72 + h] = (bf16)acc[rt][ct][r];
        }
    }
    __syncthreads();
    {   // vt[bb][h][t0..t0+31], coalesced 16B writes
        int h  = tid >> 2;          // 0..63
        int tc = (tid & 3) * 8;     // 0,8,16,24
        bf16x8 v;
        #pragma unroll
        for (int i = 0; i < 8; ++i) v[i] = Vsm[(tc + i) * 72 + h];
        *(bf16x8*)&vt[(size_t)bb * HH_ * TT_ + (size_t)h * TT_ + t0 + tc] = v;
    }
}

// ---------------- flash attention, split-K; Ps aliases Ks (LDS 35KB) ---------
// grid (80, 16): idx -> (seg, qi); each block <=4 chunks of 128 keys.
__global__ __launch_bounds__(256) void attn_kernel(const bf16* __restrict__ qb,
                                                   const bf16* __restrict__ kb,
                                                   const bf16* __restrict__ vt,
                                                   bf16* __restrict__ PO,
                                                   float* __restrict__ PL) {
    __shared__ __align__(16) bf16 KsPs[128 * 72];   // Ks; dead after QK -> Ps
    __shared__ __align__(16) bf16 Vs[64 * 136];

    const int tid  = threadIdx.x;
    const int wave = tid >> 6;
    const int lane = tid & 15;
    const int quad = (tid & 63) >> 4;
    const int idx = blockIdx.x;
    const int bb  = blockIdx.y;
    int seg, qi;
    if (idx < 32)      { seg = 0; qi = idx; }
    else if (idx < 56) { seg = 1; qi = idx - 24; }
    else if (idx < 72) { seg = 2; qi = idx - 40; }
    else               { seg = 3; qi = idx - 48; }
    const int q0   = qi * 64;
    const int qrow = q0 + wave * 16;
    const int nch   = (seg < (qi >> 3)) ? 4 : (((qi & 7) + 2) >> 1);
    const int diagc = (seg == (qi >> 3)) ? nch - 1 : -1;
    bf16* Pw = KsPs + wave * (16 * 136);            // per-wave P region (alias)

    bf16x8 aq[2];
    #pragma unroll
    for (int step = 0; step < 2; ++step)
        aq[step] = *(const bf16x8*)&qb[(size_t)(bb * TT_ + qrow + lane) * HH_ + step * 32 + quad * 8];

    f32x4 o_acc[4];
    #pragma unroll
    for (int ht = 0; ht < 4; ++ht) o_acc[ht] = f32x4{0.f, 0.f, 0.f, 0.f};
    float l_lane[4] = {0.f, 0.f, 0.f, 0.f};

    for (int c = 0; c < nch; ++c) {
        const int s0 = seg * 512 + c * 128;
        __syncthreads();                            // prev PV reads done
        #pragma unroll
        for (int j = 0; j < 4; ++j) {               // K: 128 rows x 64 h
            int ch = tid + 256 * j;
            int row = ch >> 3, c8 = (ch & 7) * 8;
            *(bf16x8*)&KsPs[row * 72 + c8] =
                *(const bf16x8*)&kb[(size_t)(bb * TT_ + s0 + row) * HH_ + c8];
        }
        #pragma unroll
        for (int j = 0; j < 4; ++j) {               // V^T: 64 rows(h) x 128 s
            int ch = tid + 256 * j;
            int h = ch >> 4, c8 = (ch & 15) * 8;
            *(bf16x8*)&Vs[h * 136 + c8] =
                *(const bf16x8*)&vt[(size_t)bb * HH_ * TT_ + (size_t)h * TT_ + s0 + c8];
        }
        __syncthreads();

        f32x4 sfr[8];
        #pragma unroll
        for (int nt = 0; nt < 8; ++nt) sfr[nt] = f32x4{0.f, 0.f, 0.f, 0.f};
        #pragma unroll
        for (int step = 0; step < 2; ++step)
            #pragma unroll
            for (int nt = 0; nt < 8; ++nt) {
                bf16x8 bk = *(const bf16x8*)&KsPs[(nt * 16 + lane) * 72 + step * 32 + quad * 8];
                sfr[nt] = __builtin_amdgcn_mfma_f32_16x16x32_bf16(aq[step], bk, sfr[nt], 0, 0, 0);
            }

        // max-free softmax: e = 2^(s * scale/ln2); no cross-lane ops
        const bool msk = (c == diagc);
        #pragma unroll
        for (int r = 0; r < 4; ++r) {
            const int rowg = qrow + quad * 4 + r;
            #pragma unroll
            for (int nt = 0; nt < 8; ++nt) {
                float e = __builtin_amdgcn_exp2f(sfr[nt][r] * SCALE2);
                if (msk && (s0 + nt * 16 + lane) > rowg) e = 0.f;
                sfr[nt][r] = e;
                l_lane[r] += e;
            }
        }

        __syncthreads();                            // all QK reads of Ks done
        #pragma unroll
        for (int nt = 0; nt < 8; ++nt)
            #pragma unroll
            for (int r = 0; r < 4; ++r)
                Pw[(quad * 4 + r) * 136 + nt * 16 + lane] = (bf16)sfr[nt][r];

        #pragma unroll
        for (int step = 0; step < 4; ++step) {
            bf16x8 ap = *(const bf16x8*)&Pw[lane * 136 + step * 32 + quad * 8];
            #pragma unroll
            for (int ht = 0; ht < 4; ++ht) {
                bf16x8 bv = *(const bf16x8*)&Vs[(ht * 16 + lane) * 136 + step * 32 + quad * 8];
                o_acc[ht] = __builtin_amdgcn_mfma_f32_16x16x32_bf16(ap, bv, o_acc[ht], 0, 0, 0);
            }
        }
    }

    // epilogue: unnormalized partials
    const size_t p = (size_t)bb * 80 + idx;
    #pragma unroll
    for (int ht = 0; ht < 4; ++ht)
        #pragma unroll
        for (int r = 0; r < 4; ++r)
            PO[p * 4096 + (size_t)(wave * 16 + quad * 4 + r) * 64 + ht * 16 + lane] = (bf16)o_acc[ht][r];
    #pragma unroll
    for (int r = 0; r < 4; ++r) {
        float l = l_lane[r];
        l += __shfl_xor(l, 1);
        l += __shfl_xor(l, 2);
        l += __shfl_xor(l, 4);
        l += __shfl_xor(l, 8);
        if (lane == 0) PL[p * 64 + wave * 16 + quad * 4 + r] = l;
    }
}

// ---------------- combine: sum partials over segments, normalize -------------
__global__ __launch_bounds__(256) void combine_kernel(const bf16* __restrict__ PO,
                                                      const float* __restrict__ PL,
                                                      float* __restrict__ out) {
    const int qi = blockIdx.x, bb = blockIdx.y;
    const int tid = threadIdx.x;
    const int r  = tid >> 2;
    const int cb = (tid & 3) * 16;
    const int ns = (qi >> 3) + 1;
    const int off[4] = {0, 32, 56, 72};

    float acc[16];
    #pragma unroll
    for (int i = 0; i < 16; ++i) acc[i] = 0.f;
    float l = 0.f;
    for (int s = 0; s < ns; ++s) {
        const size_t p = (size_t)bb * 80 + off[s] + qi - 8 * s;
        l += PL[p * 64 + r];
        const bf16* po = &PO[p * 4096 + (size_t)r * 64 + cb];
        bf16x8 a0 = *(const bf16x8*)po;
        bf16x8 a1 = *(const bf16x8*)(po + 8);
        #pragma unroll
        for (int i = 0; i < 8; ++i) { acc[i] += (float)a0[i]; acc[8 + i] += (float)a1[i]; }
    }
    const float inv = 1.0f / l;
    float* dst = &out[(size_t)(bb * TT_ + qi * 64 + r) * HH_ + cb];
    #pragma unroll
    for (int v = 0; v < 4; ++v) {
        float4 o = {acc[v * 4] * inv, acc[v * 4 + 1] * inv, acc[v * 4 + 2] * inv, acc[v * 4 + 3] * inv};
        *(float4*)(dst + v * 4) = o;
    }
}

extern "C" void kernel_launch(void* const* d_in, const int* in_sizes, int n_in,
                              void* d_out, int out_size, void* d_ws, size_t ws_size,
                              hipStream_t stream) {
    const float* x  = (const float*)d_in[0];
    const float* Wq = (const float*)d_in[1];
    const float* Wk = (const float*)d_in[2];
    const float* Wv = (const float*)d_in[3];
    float* out = (float*)d_out;

    char* ws = (char*)d_ws;
    bf16*  qb = (bf16*)(ws);                       // 4 MiB
    bf16*  kb = (bf16*)(ws + 4194304);             // 4 MiB
    bf16*  vt = (bf16*)(ws + 8388608);             // 4 MiB  V^T [bb][h][t]
    bf16*  Wt = (bf16*)(ws + 12582912);            // 384 KiB
    bf16*  PO = (bf16*)(ws + 12976128);            // 1280*4096*2 = 10.5 MiB
    float* PL = (float*)(ws + 23461888);           // 1280*64*4 = 320 KiB

    prep_w<<<48, 256, 0, stream>>>(Wq, Wk, Wv, Wt);
    qkv_kernel<<<1024, 256, 0, stream>>>(x, Wt, qb, kb, vt);
    attn_kernel<<<dim3(80, 16), 256, 0, stream>>>(qb, kb, vt, PO, PL);
    combine_kernel<<<dim3(32, 16), 256, 0, stream>>>(PO, PL, out);
}

// Round 9
// 281.966 us; speedup vs baseline: 1.0032x; 1.0032x over previous
//
#include <hip/hip_runtime.h>

typedef __bf16 bf16;
typedef __bf16 bf16x4 __attribute__((ext_vector_type(4)));
typedef __bf16 bf16x8 __attribute__((ext_vector_type(8)));
typedef float f32x4 __attribute__((ext_vector_type(4)));

#define TT_ 2048
#define CC_ 1024
#define HH_ 64

// scale * 1/ln(2): softmax via exp2, no max subtraction (|s|<~3, fp32-safe)
#define SCALE2 0.045084221f

// async 16B global->LDS DMA (no VGPR transit, deep HW queue)
__device__ __forceinline__ void load16(const void* g, void* l) {
    __builtin_amdgcn_global_load_lds(
        (const __attribute__((address_space(1))) unsigned int*)g,
        (__attribute__((address_space(3))) unsigned int*)l, 16, 0, 0);
}

// ---------------- prep: Wt[m][n][k] = W_m[k][n], fp32 -> bf16, LDS transpose --
__global__ __launch_bounds__(256) void prep_w(const float* __restrict__ Wq,
                                              const float* __restrict__ Wk,
                                              const float* __restrict__ Wv,
                                              bf16* __restrict__ Wt) {
    __shared__ bf16 Ls[64 * 65];
    const int m  = blockIdx.x >> 4;
    const int k0 = (blockIdx.x & 15) * 64;
    const float* W = (m == 0) ? Wq : (m == 1) ? Wk : Wv;
    const int tid = threadIdx.x;
    #pragma unroll
    for (int j = 0; j < 4; ++j) {
        int idx = tid + 256 * j;
        int r   = idx >> 4;
        int c4  = (idx & 15) * 4;
        float4 w = *(const float4*)&W[(size_t)(k0 + r) * HH_ + c4];
        Ls[r * 65 + c4 + 0] = (bf16)w.x;
        Ls[r * 65 + c4 + 1] = (bf16)w.y;
        Ls[r * 65 + c4 + 2] = (bf16)w.z;
        Ls[r * 65 + c4 + 3] = (bf16)w.w;
    }
    __syncthreads();
    #pragma unroll
    for (int j = 0; j < 4; ++j) {
        int idx = tid + 256 * j;
        int n   = idx >> 4;
        int kc  = (idx & 15) * 4;
        bf16x4 v;
        #pragma unroll
        for (int i = 0; i < 4; ++i) v[i] = Ls[(kc + i) * 65 + n];
        *(bf16x4*)&Wt[m * 65536 + n * 1024 + k0 + kc] = v;
    }
}

// ---------------- fused QKV: global_load_lds staging, BK=32, M-tile 64 -------
// 512 blocks (4/CU, LDS 40KB), dbuf, 1 barrier/iter. A(x fp32) and B(Wt bf16)
// both DMA'd to LDS; XOR chunk swizzle since DMA layout is lane-contiguous.
__global__ __launch_bounds__(256) void qkv_kernel(const float* __restrict__ x,
                                                  const bf16* __restrict__ Wt,
                                                  bf16* __restrict__ qb,
                                                  bf16* __restrict__ kb,
                                                  bf16* __restrict__ vt) {
    __shared__ __align__(16) float Xs[2][64 * 32];   // 8 KB/buf, 32B-slot swizzle q^(r&3)
    __shared__ __align__(16) bf16  Ws[2][192 * 32];  // 12 KB/buf, 16B-chunk swizzle ci^(n&3)
    const int tid  = threadIdx.x;
    const int wave = tid >> 6;
    const int lane = tid & 15;
    const int quad = (tid & 63) >> 4;
    const int m0   = blockIdx.x * 64;

    f32x4 acc[4][3];
    #pragma unroll
    for (int i = 0; i < 4; ++i)
        #pragma unroll
        for (int j = 0; j < 3; ++j) acc[i][j] = f32x4{0.f, 0.f, 0.f, 0.f};

    // stage tile kt (32 k-cols) into buffer b: A 512 chunks, B 768 chunks
    auto stage = [&](int kt, int b) {
        #pragma unroll
        for (int j = 0; j < 2; ++j) {          // A: 64 rows x 8 chunks(16B)
            int c  = j * 256 + tid;
            int r  = c >> 3, ci = c & 7;
            int p  = ci >> 1, half = ci & 1;
            int q  = p ^ (r & 3);              // logical 32B slot
            load16(&x[(size_t)(m0 + r) * CC_ + kt * 32 + q * 8 + half * 4],
                   (char*)&Xs[b][0] + c * 16);
        }
        #pragma unroll
        for (int j = 0; j < 3; ++j) {          // B: 192 rows x 4 chunks(16B)
            int c  = j * 256 + tid;
            int n  = c >> 2, ci = c & 3;
            int lc = ci ^ (n & 3);             // logical 16B chunk
            load16(&Wt[(size_t)n * 1024 + kt * 32 + lc * 8],
                   (char*)&Ws[b][0] + c * 16);
        }
    };

    stage(0, 0);
    __syncthreads();                           // drains vmcnt(0) before barrier

    for (int kt = 0; kt < 32; ++kt) {
        const int cur = kt & 1;
        if (kt < 31) stage(kt + 1, cur ^ 1);   // async DMA overlaps compute below
        bf16x8 bfr[3];
        #pragma unroll
        for (int ct = 0; ct < 3; ++ct) {
            int n = wave * 48 + ct * 16 + lane;
            int phys = quad ^ (n & 3);
            bfr[ct] = *(const bf16x8*)((const char*)&Ws[cur][0] + n * 64 + phys * 16);
        }
        #pragma unroll
        for (int rt = 0; rt < 4; ++rt) {
            int r = rt * 16 + lane;
            int p = quad ^ (r & 3);
            const float* ap = (const float*)((const char*)&Xs[cur][0] + r * 128 + p * 32);
            float4 a0 = *(const float4*)ap;
            float4 a1 = *(const float4*)(ap + 4);
            bf16x8 af = {(bf16)a0.x, (bf16)a0.y, (bf16)a0.z, (bf16)a0.w,
                         (bf16)a1.x, (bf16)a1.y, (bf16)a1.z, (bf16)a1.w};
            #pragma unroll
            for (int ct = 0; ct < 3; ++ct)
                acc[rt][ct] = __builtin_amdgcn_mfma_f32_16x16x32_bf16(af, bfr[ct], acc[rt][ct], 0, 0, 0);
        }
        __syncthreads();                       // drain next-tile DMA + sync
    }

    // epilogue: C/D layout col=lane, row=quad*4+r; V transposed via LDS reuse
    bf16* Vsm = (bf16*)&Xs[0][0];              // 64 x 72 bf16 = 9 KB region
    const int bb = m0 >> 11;
    const int t0 = m0 & 2047;
    #pragma unroll
    for (int ct = 0; ct < 3; ++ct) {
        int c0 = wave * 48 + ct * 16;
        if (c0 < 128) {
            bf16* outp = (c0 < 64) ? qb : kb;
            int h = (c0 & 63) + lane;
            #pragma unroll
            for (int rt = 0; rt < 4; ++rt)
                #pragma unroll
                for (int r = 0; r < 4; ++r)
                    outp[(size_t)(m0 + rt * 16 + quad * 4 + r) * HH_ + h] = (bf16)acc[rt][ct][r];
        } else {
            int h = (c0 - 128) + lane;
            #pragma unroll
            for (int rt = 0; rt < 4; ++rt)
                #pragma unroll
                for (int r = 0; r < 4; ++r)
                    Vsm[(rt * 16 + quad * 4 + r) * 72 + h] = (bf16)acc[rt][ct][r];
        }
    }
    __syncthreads();
    {   // vt[bb][h][t0..t0+63], coalesced 16B writes
        int h  = tid >> 2;
        int tc = (tid & 3) * 16;
        bf16x8 v0, v1;
        #pragma unroll
        for (int i = 0; i < 8; ++i) v0[i] = Vsm[(tc + i) * 72 + h];
        #pragma unroll
        for (int i = 0; i < 8; ++i) v1[i] = Vsm[(tc + 8 + i) * 72 + h];
        bf16* dst = &vt[(size_t)bb * HH_ * TT_ + (size_t)h * TT_ + t0 + tc];
        *(bf16x8*)dst = v0;
        *(bf16x8*)(dst + 8) = v1;
    }
}

// ---------------- flash attention, split-K; Ps aliases Ks (LDS 35KB) ---------
// grid (80, 16): idx -> (seg, qi); each block <=4 chunks of 128 keys.
__global__ __launch_bounds__(256) void attn_kernel(const bf16* __restrict__ qb,
                                                   const bf16* __restrict__ kb,
                                                   const bf16* __restrict__ vt,
                                                   bf16* __restrict__ PO,
                                                   float* __restrict__ PL) {
    __shared__ __align__(16) bf16 KsPs[128 * 72];   // Ks; dead after QK -> Ps
    __shared__ __align__(16) bf16 Vs[64 * 136];

    const int tid  = threadIdx.x;
    const int wave = tid >> 6;
    const int lane = tid & 15;
    const int quad = (tid & 63) >> 4;
    const int idx = blockIdx.x;
    const int bb  = blockIdx.y;
    int seg, qi;
    if (idx < 32)      { seg = 0; qi = idx; }
    else if (idx < 56) { seg = 1; qi = idx - 24; }
    else if (idx < 72) { seg = 2; qi = idx - 40; }
    else               { seg = 3; qi = idx - 48; }
    const int q0   = qi * 64;
    const int qrow = q0 + wave * 16;
    const int nch   = (seg < (qi >> 3)) ? 4 : (((qi & 7) + 2) >> 1);
    const int diagc = (seg == (qi >> 3)) ? nch - 1 : -1;
    bf16* Pw = KsPs + wave * (16 * 136);            // per-wave P region (alias)

    bf16x8 aq[2];
    #pragma unroll
    for (int step = 0; step < 2; ++step)
        aq[step] = *(const bf16x8*)&qb[(size_t)(bb * TT_ + qrow + lane) * HH_ + step * 32 + quad * 8];

    f32x4 o_acc[4];
    #pragma unroll
    for (int ht = 0; ht < 4; ++ht) o_acc[ht] = f32x4{0.f, 0.f, 0.f, 0.f};
    float l_lane[4] = {0.f, 0.f, 0.f, 0.f};

    for (int c = 0; c < nch; ++c) {
        const int s0 = seg * 512 + c * 128;
        __syncthreads();                            // prev PV reads done
        #pragma unroll
        for (int j = 0; j < 4; ++j) {               // K: 128 rows x 64 h
            int ch = tid + 256 * j;
            int row = ch >> 3, c8 = (ch & 7) * 8;
            *(bf16x8*)&KsPs[row * 72 + c8] =
                *(const bf16x8*)&kb[(size_t)(bb * TT_ + s0 + row) * HH_ + c8];
        }
        #pragma unroll
        for (int j = 0; j < 4; ++j) {               // V^T: 64 rows(h) x 128 s
            int ch = tid + 256 * j;
            int h = ch >> 4, c8 = (ch & 15) * 8;
            *(bf16x8*)&Vs[h * 136 + c8] =
                *(const bf16x8*)&vt[(size_t)bb * HH_ * TT_ + (size_t)h * TT_ + s0 + c8];
        }
        __syncthreads();

        f32x4 sfr[8];
        #pragma unroll
        for (int nt = 0; nt < 8; ++nt) sfr[nt] = f32x4{0.f, 0.f, 0.f, 0.f};
        #pragma unroll
        for (int step = 0; step < 2; ++step)
            #pragma unroll
            for (int nt = 0; nt < 8; ++nt) {
                bf16x8 bk = *(const bf16x8*)&KsPs[(nt * 16 + lane) * 72 + step * 32 + quad * 8];
                sfr[nt] = __builtin_amdgcn_mfma_f32_16x16x32_bf16(aq[step], bk, sfr[nt], 0, 0, 0);
            }

        // max-free softmax: e = 2^(s * scale/ln2); no cross-lane ops
        const bool msk = (c == diagc);
        #pragma unroll
        for (int r = 0; r < 4; ++r) {
            const int rowg = qrow + quad * 4 + r;
            #pragma unroll
            for (int nt = 0; nt < 8; ++nt) {
                float e = __builtin_amdgcn_exp2f(sfr[nt][r] * SCALE2);
                if (msk && (s0 + nt * 16 + lane) > rowg) e = 0.f;
                sfr[nt][r] = e;
                l_lane[r] += e;
            }
        }

        __syncthreads();                            // all QK reads of Ks done
        #pragma unroll
        for (int nt = 0; nt < 8; ++nt)
            #pragma unroll
            for (int r = 0; r < 4; ++r)
                Pw[(quad * 4 + r) * 136 + nt * 16 + lane] = (bf16)sfr[nt][r];

        #pragma unroll
        for (int step = 0; step < 4; ++step) {
            bf16x8 ap = *(const bf16x8*)&Pw[lane * 136 + step * 32 + quad * 8];
            #pragma unroll
            for (int ht = 0; ht < 4; ++ht) {
                bf16x8 bv = *(const bf16x8*)&Vs[(ht * 16 + lane) * 136 + step * 32 + quad * 8];
                o_acc[ht] = __builtin_amdgcn_mfma_f32_16x16x32_bf16(ap, bv, o_acc[ht], 0, 0, 0);
            }
        }
    }

    // epilogue: unnormalized partials
    const size_t p = (size_t)bb * 80 + idx;
    #pragma unroll
    for (int ht = 0; ht < 4; ++ht)
        #pragma unroll
        for (int r = 0; r < 4; ++r)
            PO[p * 4096 + (size_t)(wave * 16 + quad * 4 + r) * 64 + ht * 16 + lane] = (bf16)o_acc[ht][r];
    #pragma unroll
    for (int r = 0; r < 4; ++r) {
        float l = l_lane[r];
        l += __shfl_xor(l, 1);
        l += __shfl_xor(l, 2);
        l += __shfl_xor(l, 4);
        l += __shfl_xor(l, 8);
        if (lane == 0) PL[p * 64 + wave * 16 + quad * 4 + r] = l;
    }
}

// ---------------- combine: sum partials over segments, normalize -------------
__global__ __launch_bounds__(256) void combine_kernel(const bf16* __restrict__ PO,
                                                      const float* __restrict__ PL,
                                                      float* __restrict__ out) {
    const int qi = blockIdx.x, bb = blockIdx.y;
    const int tid = threadIdx.x;
    const int r  = tid >> 2;
    const int cb = (tid & 3) * 16;
    const int ns = (qi >> 3) + 1;
    const int off[4] = {0, 32, 56, 72};

    float acc[16];
    #pragma unroll
    for (int i = 0; i < 16; ++i) acc[i] = 0.f;
    float l = 0.f;
    for (int s = 0; s < ns; ++s) {
        const size_t p = (size_t)bb * 80 + off[s] + qi - 8 * s;
        l += PL[p * 64 + r];
        const bf16* po = &PO[p * 4096 + (size_t)r * 64 + cb];
        bf16x8 a0 = *(const bf16x8*)po;
        bf16x8 a1 = *(const bf16x8*)(po + 8);
        #pragma unroll
        for (int i = 0; i < 8; ++i) { acc[i] += (float)a0[i]; acc[8 + i] += (float)a1[i]; }
    }
    const float inv = 1.0f / l;
    float* dst = &out[(size_t)(bb * TT_ + qi * 64 + r) * HH_ + cb];
    #pragma unroll
    for (int v = 0; v < 4; ++v) {
        float4 o = {acc[v * 4] * inv, acc[v * 4 + 1] * inv, acc[v * 4 + 2] * inv, acc[v * 4 + 3] * inv};
        *(float4*)(dst + v * 4) = o;
    }
}

extern "C" void kernel_launch(void* const* d_in, const int* in_sizes, int n_in,
                              void* d_out, int out_size, void* d_ws, size_t ws_size,
                              hipStream_t stream) {
    const float* x  = (const float*)d_in[0];
    const float* Wq = (const float*)d_in[1];
    const float* Wk = (const float*)d_in[2];
    const float* Wv = (const float*)d_in[3];
    float* out = (float*)d_out;

    char* ws = (char*)d_ws;
    bf16*  qb = (bf16*)(ws);                       // 4 MiB
    bf16*  kb = (bf16*)(ws + 4194304);             // 4 MiB
    bf16*  vt = (bf16*)(ws + 8388608);             // 4 MiB  V^T [bb][h][t]
    bf16*  Wt = (bf16*)(ws + 12582912);            // 384 KiB
    bf16*  PO = (bf16*)(ws + 12976128);            // 1280*4096*2 = 10.5 MiB
    float* PL = (float*)(ws + 23461888);           // 1280*64*4 = 320 KiB

    prep_w<<<48, 256, 0, stream>>>(Wq, Wk, Wv, Wt);
    qkv_kernel<<<512, 256, 0, stream>>>(x, Wt, qb, kb, vt);
    attn_kernel<<<dim3(80, 16), 256, 0, stream>>>(qb, kb, vt, PO, PL);
    combine_kernel<<<dim3(32, 16), 256, 0, stream>>>(PO, PL, out);
}